// Round 1
// baseline (475.522 us; speedup 1.0000x reference)
//
#include <hip/hip_runtime.h>

#define B_ 8
#define C_ 512
#define IC_ 256
#define P_ 4096
#define MSHIFT 44.0f

typedef unsigned short u16;
typedef short v8s __attribute__((ext_vector_type(8)));
typedef float v4f __attribute__((ext_vector_type(4)));

__device__ inline u16 f2bf(float f) {
    unsigned u = __float_as_uint(f);
    u += 0x7fffu + ((u >> 16) & 1u);
    return (u16)(u >> 16);
}

// ---------------- Xsum[b][c] = sum_p x[b][c][p] ----------------
__global__ __launch_bounds__(256) void k_xsum(const float* __restrict__ x, float* __restrict__ Xsum) {
    int bc = blockIdx.x;  // b*C + c
    const float* row = x + (size_t)bc * P_;
    float s = 0.f;
    for (int k = threadIdx.x * 4; k < P_; k += 256 * 4) {
        v4f v = *reinterpret_cast<const v4f*>(row + k);
        s += v.x + v.y + v.z + v.w;
    }
    for (int off = 1; off < 64; off <<= 1) s += __shfl_xor(s, off, 64);
    __shared__ float ps[4];
    if ((threadIdx.x & 63) == 0) ps[threadIdx.x >> 6] = s;
    __syncthreads();
    if (threadIdx.x == 0) Xsum[bc] = ps[0] + ps[1] + ps[2] + ps[3];
}

// ---------------- q/k 1x1-conv GEMM: out[b][p][o] = bf16( sum_c w[o][c] x[(b+roll)%8][c][p] + bias[o] ) ----------------
// block: 256 thr = 4 waves (2x2), tile 128o x 128p, K-step 32.
__global__ __launch_bounds__(256) void k_qk(const float* __restrict__ w, const float* __restrict__ bias,
                                            const float* __restrict__ x, u16* __restrict__ out, int roll) {
    __shared__ u16 w_lds[128 * 40];  // padded stride 40 (bank-friendly, 16B aligned rows)
    __shared__ u16 x_lds[128 * 40];
    const int tid = threadIdx.x;
    const int l = tid & 63;
    const int wv = tid >> 6;
    const int wo = (wv >> 1) * 64;
    const int wp = (wv & 1) * 64;
    const int p0 = blockIdx.x * 128;
    const int o0 = blockIdx.y * 128;
    const int b = blockIdx.z;
    const int bx = (b + roll) & 7;
    const float* xb = x + (size_t)bx * C_ * P_;

    v4f acc[4][4];
#pragma unroll
    for (int i = 0; i < 4; i++)
#pragma unroll
        for (int j = 0; j < 4; j++) { acc[i][j].x = 0.f; acc[i][j].y = 0.f; acc[i][j].z = 0.f; acc[i][j].w = 0.f; }

    for (int kc = 0; kc < C_; kc += 32) {
        __syncthreads();
        // stage w tile: 128 rows(o) x 32 c (fp32 -> bf16)
#pragma unroll
        for (int it = 0; it < 4; ++it) {
            int flat = it * 256 + tid;
            int row = flat >> 3, ch = flat & 7;
            v4f wv4 = *reinterpret_cast<const v4f*>(w + (size_t)(o0 + row) * C_ + kc + ch * 4);
            uint2 pk;
            pk.x = f2bf(wv4.x) | ((unsigned)f2bf(wv4.y) << 16);
            pk.y = f2bf(wv4.z) | ((unsigned)f2bf(wv4.w) << 16);
            *reinterpret_cast<uint2*>(&w_lds[row * 40 + ch * 4]) = pk;
        }
        // stage x tile transposed: LDS [p][c] (c contiguous), global reads coalesced along p
#pragma unroll
        for (int it = 0; it < 4; ++it) {
            int flat = it * 256 + tid;
            int p = flat & 127;
            int cq = flat >> 7;  // 0..7 -> c offset cq*4
            const float* src = xb + (size_t)(kc + cq * 4) * P_ + p0 + p;
            float a0 = src[0], a1 = src[P_], a2 = src[2 * P_], a3 = src[3 * P_];
            uint2 pk;
            pk.x = f2bf(a0) | ((unsigned)f2bf(a1) << 16);
            pk.y = f2bf(a2) | ((unsigned)f2bf(a3) << 16);
            *reinterpret_cast<uint2*>(&x_lds[p * 40 + cq * 4]) = pk;
        }
        __syncthreads();
        v8s a[4];
#pragma unroll
        for (int mf = 0; mf < 4; ++mf)
            a[mf] = *reinterpret_cast<const v8s*>(&w_lds[(wo + mf * 16 + (l & 15)) * 40 + (l >> 4) * 8]);
#pragma unroll
        for (int nf = 0; nf < 4; ++nf) {
            v8s bf = *reinterpret_cast<const v8s*>(&x_lds[(wp + nf * 16 + (l & 15)) * 40 + (l >> 4) * 8]);
#pragma unroll
            for (int mf = 0; mf < 4; ++mf)
                acc[mf][nf] = __builtin_amdgcn_mfma_f32_16x16x32_bf16(a[mf], bf, acc[mf][nf], 0, 0, 0);
        }
    }
    // epilogue: D col(p)=lane&15, row(o)=(lane>>4)*4+reg -> pack 4 consecutive o as bf16x4
#pragma unroll
    for (int mf = 0; mf < 4; ++mf) {
        int ob = o0 + wo + mf * 16 + (l >> 4) * 4;
        v4f bi = *reinterpret_cast<const v4f*>(bias + ob);
#pragma unroll
        for (int nf = 0; nf < 4; ++nf) {
            int p = p0 + wp + nf * 16 + (l & 15);
            v4f v = acc[mf][nf];
            uint2 pk;
            pk.x = f2bf(v.x + bi.x) | ((unsigned)f2bf(v.y + bi.y) << 16);
            pk.y = f2bf(v.z + bi.z) | ((unsigned)f2bf(v.w + bi.w) << 16);
            *reinterpret_cast<uint2*>(&out[((size_t)b * P_ + p) * IC_ + ob]) = pk;
        }
    }
}

// ---------------- f = Q K^T passes. PASS1: srow[b][i] += sum_j exp(f-M). PASS2: colsum[b][j] += sum_i exp(f-M)/srow[i]. ----------------
// grid (2 colchunks, 32 rowblocks, 8 b); block 256 = 4 waves; wave owns 32 rows; 32 column tiles of 64.
template <int PASS>
__global__ __launch_bounds__(256) void k_f(const u16* __restrict__ Q, const u16* __restrict__ K,
                                           float* __restrict__ srow, float* __restrict__ colsum) {
    __shared__ u16 K_lds[64 * 264];  // stride 264 elems: 16B-aligned rows, conflict-free b128
    __shared__ float cp[4][64];
    const int tid = threadIdx.x;
    const int l = tid & 63;
    const int wv = tid >> 6;
    const int b = blockIdx.z;
    const int i0 = blockIdx.y * 128 + wv * 32;
    const int jbase = blockIdx.x * 2048;

    // A fragments: 32 rows x 256 ic, kept in registers for the whole sweep
    v8s a[2][8];
#pragma unroll
    for (int mf = 0; mf < 2; ++mf) {
        const u16* qrow = Q + ((size_t)b * P_ + i0 + mf * 16 + (l & 15)) * IC_ + (l >> 4) * 8;
#pragma unroll
        for (int s = 0; s < 8; ++s)
            a[mf][s] = *reinterpret_cast<const v8s*>(qrow + s * 32);
    }
    float racc[2][4];  // PASS1: row-sum accum; PASS2: 1/srow
    if (PASS == 1) {
#pragma unroll
        for (int mf = 0; mf < 2; ++mf)
#pragma unroll
            for (int r = 0; r < 4; ++r) racc[mf][r] = 0.f;
    } else {
#pragma unroll
        for (int mf = 0; mf < 2; ++mf)
#pragma unroll
            for (int r = 0; r < 4; ++r)
                racc[mf][r] = 1.0f / srow[(size_t)b * P_ + i0 + mf * 16 + (l >> 4) * 4 + r];
    }

    for (int t = 0; t < 32; ++t) {
        int j0 = jbase + t * 64;
        __syncthreads();
        if (PASS == 2 && t > 0 && tid < 64) {
            float sc = cp[0][tid] + cp[1][tid] + cp[2][tid] + cp[3][tid];
            atomicAdd(&colsum[(size_t)b * P_ + j0 - 64 + tid], sc);
        }
        {  // stage K tile 64 cols x 256 ic
            int r8 = tid >> 5, ch = tid & 31;
#pragma unroll
            for (int p8 = 0; p8 < 8; ++p8) {
                int row = p8 * 8 + r8;
                uint4 v = *reinterpret_cast<const uint4*>(K + ((size_t)b * P_ + j0 + row) * IC_ + ch * 8);
                *reinterpret_cast<uint4*>(&K_lds[row * 264 + ch * 8]) = v;
            }
        }
        __syncthreads();
        v4f acc[2][4];
#pragma unroll
        for (int mf = 0; mf < 2; ++mf)
#pragma unroll
            for (int nf = 0; nf < 4; ++nf) { acc[mf][nf].x = 0.f; acc[mf][nf].y = 0.f; acc[mf][nf].z = 0.f; acc[mf][nf].w = 0.f; }
#pragma unroll
        for (int s = 0; s < 8; ++s) {
#pragma unroll
            for (int nf = 0; nf < 4; ++nf) {
                v8s bf = *reinterpret_cast<const v8s*>(&K_lds[(nf * 16 + (l & 15)) * 264 + s * 32 + (l >> 4) * 8]);
                acc[0][nf] = __builtin_amdgcn_mfma_f32_16x16x32_bf16(a[0][s], bf, acc[0][nf], 0, 0, 0);
                acc[1][nf] = __builtin_amdgcn_mfma_f32_16x16x32_bf16(a[1][s], bf, acc[1][nf], 0, 0, 0);
            }
        }
        if (PASS == 1) {
#pragma unroll
            for (int mf = 0; mf < 2; ++mf) {
                float part[4] = {0.f, 0.f, 0.f, 0.f};
#pragma unroll
                for (int nf = 0; nf < 4; ++nf) {
                    part[0] += __expf(acc[mf][nf].x - MSHIFT);
                    part[1] += __expf(acc[mf][nf].y - MSHIFT);
                    part[2] += __expf(acc[mf][nf].z - MSHIFT);
                    part[3] += __expf(acc[mf][nf].w - MSHIFT);
                }
#pragma unroll
                for (int r = 0; r < 4; ++r) {
                    float v = part[r];
                    v += __shfl_xor(v, 1, 64);
                    v += __shfl_xor(v, 2, 64);
                    v += __shfl_xor(v, 4, 64);
                    v += __shfl_xor(v, 8, 64);
                    racc[mf][r] += v;  // full 64-col tile sum for row (l>>4)*4+r (+mf*16)
                }
            }
        } else {
            float c4[4];
#pragma unroll
            for (int nf = 0; nf < 4; ++nf) {
                float s_ = 0.f;
#pragma unroll
                for (int mf = 0; mf < 2; ++mf) {
                    s_ += __expf(acc[mf][nf].x - MSHIFT) * racc[mf][0];
                    s_ += __expf(acc[mf][nf].y - MSHIFT) * racc[mf][1];
                    s_ += __expf(acc[mf][nf].z - MSHIFT) * racc[mf][2];
                    s_ += __expf(acc[mf][nf].w - MSHIFT) * racc[mf][3];
                }
                s_ += __shfl_xor(s_, 16, 64);
                s_ += __shfl_xor(s_, 32, 64);  // all lanes: 32-row sum for col (l&15) of block nf
                c4[nf] = s_;
            }
            int g = l >> 4;
            float vout = (g == 0) ? c4[0] : ((g == 1) ? c4[1] : ((g == 2) ? c4[2] : c4[3]));
            cp[wv][l] = vout;
        }
    }
    __syncthreads();
    if (PASS == 2 && tid < 64) {
        float sc = cp[0][tid] + cp[1][tid] + cp[2][tid] + cp[3][tid];
        atomicAdd(&colsum[(size_t)b * P_ + jbase + 2048 - 64 + tid], sc);
    }
    if (PASS == 1 && (l & 15) == 0) {
#pragma unroll
        for (int mf = 0; mf < 2; ++mf)
#pragma unroll
            for (int r = 0; r < 4; ++r)
                atomicAdd(&srow[(size_t)b * P_ + i0 + mf * 16 + (l >> 4) * 4 + r], racc[mf][r]);
    }
}

// ---------------- vsum[b][o] = sum_c w_g[o][c]*Xsum[(b-1)%8][c] + P*b_g[o] ----------------
__global__ __launch_bounds__(256) void k_vsum(const float* __restrict__ w_g, const float* __restrict__ b_g,
                                              const float* __restrict__ Xsum, float* __restrict__ vsum) {
    __shared__ float xs[C_];
    int b = blockIdx.x;
    int bp = (b + B_ - 1) & 7;
    for (int i = threadIdx.x; i < C_; i += 256) xs[i] = Xsum[bp * C_ + i];
    __syncthreads();
    int o = threadIdx.x;
    const float* wr = w_g + (size_t)o * C_;
    float acc = 0.f;
    for (int c = 0; c < C_; c += 4) {
        v4f wv = *reinterpret_cast<const v4f*>(wr + c);
        acc += wv.x * xs[c] + wv.y * xs[c + 1] + wv.z * xs[c + 2] + wv.w * xs[c + 3];
    }
    vsum[b * IC_ + o] = acc + (float)P_ * b_g[o];
}

// ---------------- Kv = w_W[:,IC:]*vsum + b_W ; Dv = (w_W[:,:IC]-w_W[:,IC:])*vsum ----------------
__global__ __launch_bounds__(512) void k_kd(const float* __restrict__ w_W, const float* __restrict__ b_W,
                                            const float* __restrict__ vsum, float* __restrict__ Kv, float* __restrict__ Dv) {
    __shared__ float vs[IC_];
    int b = blockIdx.x;
    for (int i = threadIdx.x; i < IC_; i += 512) vs[i] = vsum[b * IC_ + i];
    __syncthreads();
    int o = threadIdx.x;
    const float* wr = w_W + (size_t)o * (2 * IC_);
    float a = 0.f, bv = 0.f;
    for (int ic = 0; ic < IC_; ic += 4) {
        v4f w1 = *reinterpret_cast<const v4f*>(wr + ic);
        v4f w2 = *reinterpret_cast<const v4f*>(wr + IC_ + ic);
        a += w1.x * vs[ic] + w1.y * vs[ic + 1] + w1.z * vs[ic + 2] + w1.w * vs[ic + 3];
        bv += w2.x * vs[ic] + w2.y * vs[ic + 1] + w2.z * vs[ic + 2] + w2.w * vs[ic + 3];
    }
    Kv[b * C_ + o] = bv + b_W[o];
    Dv[b * C_ + o] = a - bv;
}

// ---------------- per-batch s1 = sum_p m, s2 = sum_p m^2 (m = colsum/P) ----------------
__global__ __launch_bounds__(256) void k_s12(const float* __restrict__ colsum, float* __restrict__ s12) {
    int b = blockIdx.x;
    const float invP = 1.0f / P_;
    float s1 = 0.f, s2 = 0.f;
    for (int k = threadIdx.x * 4; k < P_; k += 1024) {
        v4f v = *reinterpret_cast<const v4f*>(colsum + (size_t)b * P_ + k);
        float m0 = v.x * invP, m1 = v.y * invP, m2 = v.z * invP, m3 = v.w * invP;
        s1 += m0 + m1 + m2 + m3;
        s2 += m0 * m0 + m1 * m1 + m2 * m2 + m3 * m3;
    }
    for (int off = 1; off < 64; off <<= 1) {
        s1 += __shfl_xor(s1, off, 64);
        s2 += __shfl_xor(s2, off, 64);
    }
    __shared__ float p1[4], p2[4];
    if ((threadIdx.x & 63) == 0) { p1[threadIdx.x >> 6] = s1; p2[threadIdx.x >> 6] = s2; }
    __syncthreads();
    if (threadIdx.x == 0) {
        s12[b * 2] = p1[0] + p1[1] + p1[2] + p1[3];
        s12[b * 2 + 1] = p2[0] + p2[1] + p2[2] + p2[3];
    }
}

// ---------------- closed-form BN stats -> per (b,o) affine coeffs ----------------
__global__ __launch_bounds__(512) void k_bn(const float* __restrict__ Kv, const float* __restrict__ Dv,
                                            const float* __restrict__ s12, const float* __restrict__ gamma,
                                            const float* __restrict__ beta, float* __restrict__ alpha, float* __restrict__ ofs) {
    int o = threadIdx.x;
    const float invP = 1.0f / P_;
    float mu = 0.f, e2 = 0.f;
#pragma unroll
    for (int b = 0; b < B_; ++b) {
        float Kx = Kv[b * C_ + o], Dx = Dv[b * C_ + o];
        float m1 = s12[b * 2] * invP;      // E_p[m]
        float m2 = s12[b * 2 + 1] * invP;  // E_p[m^2]
        mu += Kx + Dx * m1;
        e2 += Kx * Kx + 2.f * Kx * Dx * m1 + Dx * Dx * m2;
    }
    mu *= 0.125f;
    e2 *= 0.125f;
    float var = e2 - mu * mu;
    float gi = gamma[o] * rsqrtf(var + 1e-5f);
    float bo = beta[o];
#pragma unroll
    for (int b = 0; b < B_; ++b) {
        alpha[b * C_ + o] = gi * Dv[b * C_ + o] * invP;  // multiplies raw colsum
        ofs[b * C_ + o] = gi * (Kv[b * C_ + o] - mu) + bo;
    }
}

// ---------------- out[b][o][p] = ofs[b,o] + alpha[b,o]*colsum[b,p] + x[b,o,p] ----------------
__global__ __launch_bounds__(256) void k_out(const float* __restrict__ x, const float* __restrict__ colsum,
                                             const float* __restrict__ alpha, const float* __restrict__ ofs,
                                             float* __restrict__ out) {
    int bo = blockIdx.x >> 2;  // b*C + o
    int qd = blockIdx.x & 3;
    int b = bo >> 9;
    int p = qd * 1024 + threadIdx.x * 4;
    float al = alpha[bo], of = ofs[bo];
    size_t base = (size_t)bo * P_ + p;
    v4f xv = *reinterpret_cast<const v4f*>(x + base);
    v4f cs = *reinterpret_cast<const v4f*>(colsum + (size_t)b * P_ + p);
    v4f r;
    r.x = of + al * cs.x + xv.x;
    r.y = of + al * cs.y + xv.y;
    r.z = of + al * cs.z + xv.z;
    r.w = of + al * cs.w + xv.w;
    *reinterpret_cast<v4f*>(out + base) = r;
}

extern "C" void kernel_launch(void* const* d_in, const int* in_sizes, int n_in,
                              void* d_out, int out_size, void* d_ws, size_t ws_size,
                              hipStream_t stream) {
    const float* x = (const float*)d_in[0];
    const float* w_theta = (const float*)d_in[1];
    const float* b_theta = (const float*)d_in[2];
    const float* w_phi = (const float*)d_in[3];
    const float* b_phi = (const float*)d_in[4];
    const float* w_g = (const float*)d_in[5];
    const float* b_g = (const float*)d_in[6];
    const float* w_W = (const float*)d_in[7];
    const float* b_W = (const float*)d_in[8];
    const float* gamma = (const float*)d_in[9];
    const float* beta = (const float*)d_in[10];
    float* out = (float*)d_out;

    u16* Q = (u16*)d_ws;
    u16* K = Q + (size_t)B_ * P_ * IC_;
    float* fb = (float*)((char*)d_ws + (size_t)2 * B_ * P_ * IC_ * 2);
    float* srow = fb;                 // B*P
    float* colsum = srow + B_ * P_;   // B*P
    float* Xsum = colsum + B_ * P_;   // B*C
    float* vsum = Xsum + B_ * C_;     // B*IC
    float* Kv = vsum + B_ * IC_;      // B*C
    float* Dv = Kv + B_ * C_;         // B*C
    float* s12 = Dv + B_ * C_;        // 16
    float* alpha = s12 + 16;          // B*C
    float* ofs = alpha + B_ * C_;     // B*C

    hipMemsetAsync(srow, 0, sizeof(float) * 2 * B_ * P_, stream);
    k_xsum<<<B_ * C_, 256, 0, stream>>>(x, Xsum);
    k_qk<<<dim3(32, 2, 8), 256, 0, stream>>>(w_theta, b_theta, x, Q, 0);
    k_qk<<<dim3(32, 2, 8), 256, 0, stream>>>(w_phi, b_phi, x, K, B_ - 1);
    k_vsum<<<B_, 256, 0, stream>>>(w_g, b_g, Xsum, vsum);
    k_kd<<<B_, 512, 0, stream>>>(w_W, b_W, vsum, Kv, Dv);
    k_f<1><<<dim3(2, 32, 8), 256, 0, stream>>>(Q, K, srow, colsum);
    k_f<2><<<dim3(2, 32, 8), 256, 0, stream>>>(Q, K, srow, colsum);
    k_s12<<<B_, 256, 0, stream>>>(colsum, s12);
    k_bn<<<1, 512, 0, stream>>>(Kv, Dv, s12, gamma, beta, alpha, ofs);
    k_out<<<B_ * C_ * 4, 256, 0, stream>>>(x, colsum, alpha, ofs, out);
}

// Round 2
// 419.645 us; speedup vs baseline: 1.1332x; 1.1332x over previous
//
#include <hip/hip_runtime.h>

#define B_ 8
#define C_ 512
#define IC_ 256
#define P_ 4096
#define MSHIFT 44.0f

typedef unsigned short u16;
typedef short v8s __attribute__((ext_vector_type(8)));
typedef float v4f __attribute__((ext_vector_type(4)));

__device__ inline u16 f2bf(float f) {
    unsigned u = __float_as_uint(f);
    u += 0x7fffu + ((u >> 16) & 1u);
    return (u16)(u >> 16);
}

typedef const __attribute__((address_space(1))) unsigned int* gp1_t;
typedef __attribute__((address_space(3))) unsigned int* lp3_t;
__device__ inline void gload_lds16(const void* g, void* l) {
    __builtin_amdgcn_global_load_lds((gp1_t)g, (lp3_t)l, 16, 0, 0);
}

// ---------------- Xsum[b][c] = sum_p x[b][c][p] ----------------
__global__ __launch_bounds__(256) void k_xsum(const float* __restrict__ x, float* __restrict__ Xsum) {
    int bc = blockIdx.x;
    const float* row = x + (size_t)bc * P_;
    float s = 0.f;
    for (int k = threadIdx.x * 4; k < P_; k += 256 * 4) {
        v4f v = *reinterpret_cast<const v4f*>(row + k);
        s += v.x + v.y + v.z + v.w;
    }
    for (int off = 1; off < 64; off <<= 1) s += __shfl_xor(s, off, 64);
    __shared__ float ps[4];
    if ((threadIdx.x & 63) == 0) ps[threadIdx.x >> 6] = s;
    __syncthreads();
    if (threadIdx.x == 0) Xsum[bc] = ps[0] + ps[1] + ps[2] + ps[3];
}

// ---------------- q/k 1x1-conv GEMM (both theta->Q and phi->K in one launch) ----------------
__global__ __launch_bounds__(256) void k_qk(const float* __restrict__ w_theta, const float* __restrict__ b_theta,
                                            const float* __restrict__ w_phi, const float* __restrict__ b_phi,
                                            const float* __restrict__ x, u16* __restrict__ Q, u16* __restrict__ K) {
    __shared__ u16 w_lds[128 * 40];
    __shared__ u16 x_lds[128 * 40];
    const int tid = threadIdx.x;
    const int l = tid & 63;
    const int wv = tid >> 6;
    const int wo = (wv >> 1) * 64;
    const int wp = (wv & 1) * 64;
    const int p0 = blockIdx.x * 128;
    const int o0 = blockIdx.y * 128;
    const int z = blockIdx.z;
    const int which = z >> 3;
    const int b = z & 7;
    const float* w = which ? w_phi : w_theta;
    const float* bias = which ? b_phi : b_theta;
    u16* out = which ? K : Q;
    const int bx = which ? ((b + 7) & 7) : b;
    const float* xb = x + (size_t)bx * C_ * P_;

    v4f acc[4][4];
#pragma unroll
    for (int i = 0; i < 4; i++)
#pragma unroll
        for (int j = 0; j < 4; j++) { acc[i][j].x = 0.f; acc[i][j].y = 0.f; acc[i][j].z = 0.f; acc[i][j].w = 0.f; }

    for (int kc = 0; kc < C_; kc += 32) {
        __syncthreads();
#pragma unroll
        for (int it = 0; it < 4; ++it) {
            int flat = it * 256 + tid;
            int row = flat >> 3, ch = flat & 7;
            v4f wv4 = *reinterpret_cast<const v4f*>(w + (size_t)(o0 + row) * C_ + kc + ch * 4);
            uint2 pk;
            pk.x = f2bf(wv4.x) | ((unsigned)f2bf(wv4.y) << 16);
            pk.y = f2bf(wv4.z) | ((unsigned)f2bf(wv4.w) << 16);
            *reinterpret_cast<uint2*>(&w_lds[row * 40 + ch * 4]) = pk;
        }
#pragma unroll
        for (int it = 0; it < 4; ++it) {
            int flat = it * 256 + tid;
            int p = flat & 127;
            int cq = flat >> 7;
            const float* src = xb + (size_t)(kc + cq * 4) * P_ + p0 + p;
            float a0 = src[0], a1 = src[P_], a2 = src[2 * P_], a3 = src[3 * P_];
            uint2 pk;
            pk.x = f2bf(a0) | ((unsigned)f2bf(a1) << 16);
            pk.y = f2bf(a2) | ((unsigned)f2bf(a3) << 16);
            *reinterpret_cast<uint2*>(&x_lds[p * 40 + cq * 4]) = pk;
        }
        __syncthreads();
        v8s a[4];
#pragma unroll
        for (int mf = 0; mf < 4; ++mf)
            a[mf] = *reinterpret_cast<const v8s*>(&w_lds[(wo + mf * 16 + (l & 15)) * 40 + (l >> 4) * 8]);
#pragma unroll
        for (int nf = 0; nf < 4; ++nf) {
            v8s bf = *reinterpret_cast<const v8s*>(&x_lds[(wp + nf * 16 + (l & 15)) * 40 + (l >> 4) * 8]);
#pragma unroll
            for (int mf = 0; mf < 4; ++mf)
                acc[mf][nf] = __builtin_amdgcn_mfma_f32_16x16x32_bf16(a[mf], bf, acc[mf][nf], 0, 0, 0);
        }
    }
#pragma unroll
    for (int mf = 0; mf < 4; ++mf) {
        int ob = o0 + wo + mf * 16 + (l >> 4) * 4;
        v4f bi = *reinterpret_cast<const v4f*>(bias + ob);
#pragma unroll
        for (int nf = 0; nf < 4; ++nf) {
            int p = p0 + wp + nf * 16 + (l & 15);
            v4f v = acc[mf][nf];
            uint2 pk;
            pk.x = f2bf(v.x + bi.x) | ((unsigned)f2bf(v.y + bi.y) << 16);
            pk.y = f2bf(v.z + bi.z) | ((unsigned)f2bf(v.w + bi.w) << 16);
            *reinterpret_cast<uint2*>(&out[((size_t)b * P_ + p) * IC_ + ob]) = pk;
        }
    }
}

// ---------------- f = Q K^T passes, pipelined. ----------------
// 512 blocks (4 j-chunks x 16 rowblocks x 8 b), 4 waves x 64 rows, K-tiles of 64 cols.
// LDS: 2 x 32KB linear K-tile (global_load_lds, source pre-swizzled), XOR-swizzled ds_read.
template <int PASS>
__global__ __launch_bounds__(256, 2) void k_f(const u16* __restrict__ Q, const u16* __restrict__ K,
                                              float* __restrict__ srow, float* __restrict__ colsum) {
    __shared__ __align__(16) unsigned char smem[65536 + 2048];
    float* cp = (float*)(smem + 65536);  // [2][4][64]
    const int tid = threadIdx.x;
    const int l = tid & 63;
    const int wv = tid >> 6;
    // bijective XCD swizzle: co-locate all 64 blocks of one batch on one XCD (K/Q fit 4MB L2)
    int lin = blockIdx.x + blockIdx.y * 4 + blockIdx.z * 64;  // gridDim=(4,16,8)
    int nlin = (lin & 7) * 64 + (lin >> 3);
    const int jchunk = nlin & 3;
    const int yb = (nlin >> 2) & 15;
    const int b = nlin >> 6;
    const int i0 = yb * 256 + wv * 64;
    const int jbase = jchunk * 1024;
    const u16* Kb = K + (size_t)b * P_ * IC_;

    // A fragments: 64 rows x 256 ic in registers (32 v8s = 128 VGPR)
    v8s a[4][8];
#pragma unroll
    for (int mf = 0; mf < 4; ++mf) {
        const u16* qrow = Q + ((size_t)b * P_ + i0 + mf * 16 + (l & 15)) * IC_ + (l >> 4) * 8;
#pragma unroll
        for (int s = 0; s < 8; ++s)
            a[mf][s] = *reinterpret_cast<const v8s*>(qrow + s * 32);
    }
    float racc[4][4];
    if (PASS == 1) {
#pragma unroll
        for (int mf = 0; mf < 4; ++mf)
#pragma unroll
            for (int r = 0; r < 4; ++r) racc[mf][r] = 0.f;
    } else {
#pragma unroll
        for (int mf = 0; mf < 4; ++mf) {
            v4f sr = *reinterpret_cast<const v4f*>(&srow[(size_t)b * P_ + i0 + mf * 16 + (l >> 4) * 4]);
            racc[mf][0] = 1.0f / sr.x;
            racc[mf][1] = 1.0f / sr.y;
            racc[mf][2] = 1.0f / sr.z;
            racc[mf][3] = 1.0f / sr.w;
        }
    }

    // stage tile t into buffer bufsel: linear LDS dest, inverse-swizzled global source
    auto stage = [&](int t, int bufsel) {
        int j0 = jbase + t * 64;
#pragma unroll
        for (int it = 0; it < 8; ++it) {
            int slot = wv * 8192 + it * 1024 + (l << 4);  // byte within 32KB tile
            int row = slot >> 9;
            int brg = (slot & 511) ^ ((row & 7) << 4);
            const unsigned char* g = (const unsigned char*)(Kb + (size_t)(j0 + row) * IC_) + brg;
            gload_lds16(g, smem + bufsel * 32768 + wv * 8192 + it * 1024);
        }
    };

    stage(0, 0);
    asm volatile("s_waitcnt vmcnt(0)" ::: "memory");
    __syncthreads();
    int cur = 0;
    for (int t = 0; t < 16; ++t) {
        if (t < 15) stage(t + 1, cur ^ 1);
        if (PASS == 2 && t > 0 && tid < 64) {
            float* cpp = cp + ((t - 1) & 1) * 256;
            float sc = cpp[tid] + cpp[64 + tid] + cpp[128 + tid] + cpp[192 + tid];
            atomicAdd(&colsum[(size_t)b * P_ + jbase + (t - 1) * 64 + tid], sc);
        }
        v4f acc[4][4];
#pragma unroll
        for (int mf = 0; mf < 4; ++mf)
#pragma unroll
            for (int nf = 0; nf < 4; ++nf) { acc[mf][nf].x = 0.f; acc[mf][nf].y = 0.f; acc[mf][nf].z = 0.f; acc[mf][nf].w = 0.f; }
#pragma unroll
        for (int s = 0; s < 8; ++s) {
#pragma unroll
            for (int nf = 0; nf < 4; ++nf) {
                int row = nf * 16 + (l & 15);
                int byte_ = cur * 32768 + row * 512 + ((s * 64 + (l >> 4) * 16) ^ ((row & 7) << 4));
                v8s bf = *reinterpret_cast<const v8s*>(smem + byte_);
#pragma unroll
                for (int mf = 0; mf < 4; ++mf)
                    acc[mf][nf] = __builtin_amdgcn_mfma_f32_16x16x32_bf16(a[mf][s], bf, acc[mf][nf], 0, 0, 0);
            }
        }
        if (PASS == 1) {
#pragma unroll
            for (int mf = 0; mf < 4; ++mf) {
                float p0 = 0.f, p1 = 0.f, p2 = 0.f, p3 = 0.f;
#pragma unroll
                for (int nf = 0; nf < 4; ++nf) {
                    p0 += __expf(acc[mf][nf].x - MSHIFT);
                    p1 += __expf(acc[mf][nf].y - MSHIFT);
                    p2 += __expf(acc[mf][nf].z - MSHIFT);
                    p3 += __expf(acc[mf][nf].w - MSHIFT);
                }
                racc[mf][0] += p0;
                racc[mf][1] += p1;
                racc[mf][2] += p2;
                racc[mf][3] += p3;
            }
        } else {
            float c4[4];
#pragma unroll
            for (int nf = 0; nf < 4; ++nf) {
                float s_ = 0.f;
#pragma unroll
                for (int mf = 0; mf < 4; ++mf) {
                    s_ += __expf(acc[mf][nf].x - MSHIFT) * racc[mf][0];
                    s_ += __expf(acc[mf][nf].y - MSHIFT) * racc[mf][1];
                    s_ += __expf(acc[mf][nf].z - MSHIFT) * racc[mf][2];
                    s_ += __expf(acc[mf][nf].w - MSHIFT) * racc[mf][3];
                }
                s_ += __shfl_xor(s_, 16, 64);
                s_ += __shfl_xor(s_, 32, 64);
                c4[nf] = s_;
            }
            int g = l >> 4;
            float vout = (g == 0) ? c4[0] : ((g == 1) ? c4[1] : ((g == 2) ? c4[2] : c4[3]));
            cp[(t & 1) * 256 + wv * 64 + l] = vout;
        }
        asm volatile("s_waitcnt vmcnt(0)" ::: "memory");
        __syncthreads();
        cur ^= 1;
    }
    if (PASS == 2 && tid < 64) {
        float* cpp = cp + 256;  // tile 15 parity = 1
        float sc = cpp[tid] + cpp[64 + tid] + cpp[128 + tid] + cpp[192 + tid];
        atomicAdd(&colsum[(size_t)b * P_ + jbase + 15 * 64 + tid], sc);
    }
    if (PASS == 1) {
#pragma unroll
        for (int mf = 0; mf < 4; ++mf)
#pragma unroll
            for (int r = 0; r < 4; ++r) {
                float v = racc[mf][r];
                v += __shfl_xor(v, 1, 64);
                v += __shfl_xor(v, 2, 64);
                v += __shfl_xor(v, 4, 64);
                v += __shfl_xor(v, 8, 64);
                if ((l & 15) == 0)
                    atomicAdd(&srow[(size_t)b * P_ + i0 + mf * 16 + (l >> 4) * 4 + r], v);
            }
    }
}

// ---------------- vsum[b][o] = sum_c w_g[o][c]*Xsum[(b-1)%8][c] + P*b_g[o] ----------------
__global__ __launch_bounds__(256) void k_vsum(const float* __restrict__ w_g, const float* __restrict__ b_g,
                                              const float* __restrict__ Xsum, float* __restrict__ vsum) {
    __shared__ float xs[C_];
    int b = blockIdx.x;
    int bp = (b + B_ - 1) & 7;
    for (int i = threadIdx.x; i < C_; i += 256) xs[i] = Xsum[bp * C_ + i];
    __syncthreads();
    int o = threadIdx.x;
    const float* wr = w_g + (size_t)o * C_;
    float acc = 0.f;
    for (int c = 0; c < C_; c += 4) {
        v4f wv = *reinterpret_cast<const v4f*>(wr + c);
        acc += wv.x * xs[c] + wv.y * xs[c + 1] + wv.z * xs[c + 2] + wv.w * xs[c + 3];
    }
    vsum[b * IC_ + o] = acc + (float)P_ * b_g[o];
}

__global__ __launch_bounds__(512) void k_kd(const float* __restrict__ w_W, const float* __restrict__ b_W,
                                            const float* __restrict__ vsum, float* __restrict__ Kv, float* __restrict__ Dv) {
    __shared__ float vs[IC_];
    int b = blockIdx.x;
    for (int i = threadIdx.x; i < IC_; i += 512) vs[i] = vsum[b * IC_ + i];
    __syncthreads();
    int o = threadIdx.x;
    const float* wr = w_W + (size_t)o * (2 * IC_);
    float a = 0.f, bv = 0.f;
    for (int ic = 0; ic < IC_; ic += 4) {
        v4f w1 = *reinterpret_cast<const v4f*>(wr + ic);
        v4f w2 = *reinterpret_cast<const v4f*>(wr + IC_ + ic);
        a += w1.x * vs[ic] + w1.y * vs[ic + 1] + w1.z * vs[ic + 2] + w1.w * vs[ic + 3];
        bv += w2.x * vs[ic] + w2.y * vs[ic + 1] + w2.z * vs[ic + 2] + w2.w * vs[ic + 3];
    }
    Kv[b * C_ + o] = bv + b_W[o];
    Dv[b * C_ + o] = a - bv;
}

__global__ __launch_bounds__(256) void k_s12(const float* __restrict__ colsum, float* __restrict__ s12) {
    int b = blockIdx.x;
    const float invP = 1.0f / P_;
    float s1 = 0.f, s2 = 0.f;
    for (int k = threadIdx.x * 4; k < P_; k += 1024) {
        v4f v = *reinterpret_cast<const v4f*>(colsum + (size_t)b * P_ + k);
        float m0 = v.x * invP, m1 = v.y * invP, m2 = v.z * invP, m3 = v.w * invP;
        s1 += m0 + m1 + m2 + m3;
        s2 += m0 * m0 + m1 * m1 + m2 * m2 + m3 * m3;
    }
    for (int off = 1; off < 64; off <<= 1) {
        s1 += __shfl_xor(s1, off, 64);
        s2 += __shfl_xor(s2, off, 64);
    }
    __shared__ float p1[4], p2[4];
    if ((threadIdx.x & 63) == 0) { p1[threadIdx.x >> 6] = s1; p2[threadIdx.x >> 6] = s2; }
    __syncthreads();
    if (threadIdx.x == 0) {
        s12[b * 2] = p1[0] + p1[1] + p1[2] + p1[3];
        s12[b * 2 + 1] = p2[0] + p2[1] + p2[2] + p2[3];
    }
}

__global__ __launch_bounds__(512) void k_bn(const float* __restrict__ Kv, const float* __restrict__ Dv,
                                            const float* __restrict__ s12, const float* __restrict__ gamma,
                                            const float* __restrict__ beta, float* __restrict__ alpha, float* __restrict__ ofs) {
    int o = threadIdx.x;
    const float invP = 1.0f / P_;
    float mu = 0.f, e2 = 0.f;
#pragma unroll
    for (int b = 0; b < B_; ++b) {
        float Kx = Kv[b * C_ + o], Dx = Dv[b * C_ + o];
        float m1 = s12[b * 2] * invP;
        float m2 = s12[b * 2 + 1] * invP;
        mu += Kx + Dx * m1;
        e2 += Kx * Kx + 2.f * Kx * Dx * m1 + Dx * Dx * m2;
    }
    mu *= 0.125f;
    e2 *= 0.125f;
    float var = e2 - mu * mu;
    float gi = gamma[o] * rsqrtf(var + 1e-5f);
    float bo = beta[o];
#pragma unroll
    for (int b = 0; b < B_; ++b) {
        alpha[b * C_ + o] = gi * Dv[b * C_ + o] * invP;
        ofs[b * C_ + o] = gi * (Kv[b * C_ + o] - mu) + bo;
    }
}

// ---------------- out[b][o][p] = ofs[b,o] + alpha[b,o]*colsum[b,p] + x[b,o,p] ----------------
__global__ __launch_bounds__(256) void k_out(const float* __restrict__ x, const float* __restrict__ colsum,
                                             const float* __restrict__ alpha, const float* __restrict__ ofs,
                                             float* __restrict__ out) {
    int bo = blockIdx.x;  // b*C + o
    int b = bo >> 9;
    float al = alpha[bo], of = ofs[bo];
    size_t base = (size_t)bo * P_;
    const float* cb = colsum + (size_t)b * P_;
#pragma unroll
    for (int q = 0; q < 4; ++q) {
        int p = q * 1024 + threadIdx.x * 4;
        v4f xv = *reinterpret_cast<const v4f*>(x + base + p);
        v4f cs = *reinterpret_cast<const v4f*>(cb + p);
        v4f r;
        r.x = of + al * cs.x + xv.x;
        r.y = of + al * cs.y + xv.y;
        r.z = of + al * cs.z + xv.z;
        r.w = of + al * cs.w + xv.w;
        *reinterpret_cast<v4f*>(out + base + p) = r;
    }
}

extern "C" void kernel_launch(void* const* d_in, const int* in_sizes, int n_in,
                              void* d_out, int out_size, void* d_ws, size_t ws_size,
                              hipStream_t stream) {
    const float* x = (const float*)d_in[0];
    const float* w_theta = (const float*)d_in[1];
    const float* b_theta = (const float*)d_in[2];
    const float* w_phi = (const float*)d_in[3];
    const float* b_phi = (const float*)d_in[4];
    const float* w_g = (const float*)d_in[5];
    const float* b_g = (const float*)d_in[6];
    const float* w_W = (const float*)d_in[7];
    const float* b_W = (const float*)d_in[8];
    const float* gamma = (const float*)d_in[9];
    const float* beta = (const float*)d_in[10];
    float* out = (float*)d_out;

    u16* Q = (u16*)d_ws;
    u16* K = Q + (size_t)B_ * P_ * IC_;
    float* fb = (float*)((char*)d_ws + (size_t)2 * B_ * P_ * IC_ * 2);
    float* srow = fb;
    float* colsum = srow + B_ * P_;
    float* Xsum = colsum + B_ * P_;
    float* vsum = Xsum + B_ * C_;
    float* Kv = vsum + B_ * IC_;
    float* Dv = Kv + B_ * C_;
    float* s12 = Dv + B_ * C_;
    float* alpha = s12 + 16;
    float* ofs = alpha + B_ * C_;

    hipMemsetAsync(srow, 0, sizeof(float) * 2 * B_ * P_, stream);
    k_xsum<<<B_ * C_, 256, 0, stream>>>(x, Xsum);
    k_qk<<<dim3(32, 2, 16), 256, 0, stream>>>(w_theta, b_theta, w_phi, b_phi, x, Q, K);
    k_vsum<<<B_, 256, 0, stream>>>(w_g, b_g, Xsum, vsum);
    k_kd<<<B_, 512, 0, stream>>>(w_W, b_W, vsum, Kv, Dv);
    k_f<1><<<dim3(4, 16, 8), 256, 0, stream>>>(Q, K, srow, colsum);
    k_f<2><<<dim3(4, 16, 8), 256, 0, stream>>>(Q, K, srow, colsum);
    k_s12<<<B_, 256, 0, stream>>>(colsum, s12);
    k_bn<<<1, 512, 0, stream>>>(Kv, Dv, s12, gamma, beta, alpha, ofs);
    k_out<<<B_ * C_, 256, 0, stream>>>(x, colsum, alpha, ofs, out);
}

// Round 5
// 401.393 us; speedup vs baseline: 1.1847x; 1.0455x over previous
//
#include <hip/hip_runtime.h>

#define B_ 8
#define C_ 512
#define IC_ 256
#define P_ 4096
#define LOG2E 1.4426950408889634f
#define MSHIFT2 63.478581799113246f  // 44 * log2(e)

typedef unsigned short u16;
typedef short v8s __attribute__((ext_vector_type(8)));
typedef float v4f __attribute__((ext_vector_type(4)));

__device__ inline u16 f2bf(float f) {
    unsigned u = __float_as_uint(f);
    u += 0x7fffu + ((u >> 16) & 1u);
    return (u16)(u >> 16);
}

typedef const __attribute__((address_space(1))) unsigned int* gp1_t;
typedef __attribute__((address_space(3))) unsigned int* lp3_t;
__device__ inline void gload_lds16(const void* g, void* l) {
    __builtin_amdgcn_global_load_lds((gp1_t)g, (lp3_t)l, 16, 0, 0);
}

// ---------------- Xsum[b][c] = sum_p x[b][c][p] ----------------
__global__ __launch_bounds__(256) void k_xsum(const float* __restrict__ x, float* __restrict__ Xsum) {
    int bc = blockIdx.x;
    const float* row = x + (size_t)bc * P_;
    float s = 0.f;
    for (int k = threadIdx.x * 4; k < P_; k += 256 * 4) {
        v4f v = *reinterpret_cast<const v4f*>(row + k);
        s += v.x + v.y + v.z + v.w;
    }
    for (int off = 1; off < 64; off <<= 1) s += __shfl_xor(s, off, 64);
    __shared__ float ps[4];
    if ((threadIdx.x & 63) == 0) ps[threadIdx.x >> 6] = s;
    __syncthreads();
    if (threadIdx.x == 0) Xsum[bc] = ps[0] + ps[1] + ps[2] + ps[3];
}

// ---------------- q/k 1x1-conv GEMM (theta->Q scaled by log2e, phi->K) ----------------
__global__ __launch_bounds__(256) void k_qk(const float* __restrict__ w_theta, const float* __restrict__ b_theta,
                                            const float* __restrict__ w_phi, const float* __restrict__ b_phi,
                                            const float* __restrict__ x, u16* __restrict__ Q, u16* __restrict__ K) {
    __shared__ u16 w_lds[128 * 40];
    __shared__ u16 x_lds[128 * 40];
    const int tid = threadIdx.x;
    const int l = tid & 63;
    const int wv = tid >> 6;
    const int wo = (wv >> 1) * 64;
    const int wp = (wv & 1) * 64;
    const int p0 = blockIdx.x * 128;
    const int o0 = blockIdx.y * 128;
    const int z = blockIdx.z;
    const int which = z >> 3;
    const int b = z & 7;
    const float* w = which ? w_phi : w_theta;
    const float* bias = which ? b_phi : b_theta;
    u16* out = which ? K : Q;
    const float qscale = which ? 1.0f : LOG2E;  // bake exp->exp2 conversion into Q
    const int bx = which ? ((b + 7) & 7) : b;
    const float* xb = x + (size_t)bx * C_ * P_;

    v4f acc[4][4];
#pragma unroll
    for (int i = 0; i < 4; i++)
#pragma unroll
        for (int j = 0; j < 4; j++) { acc[i][j].x = 0.f; acc[i][j].y = 0.f; acc[i][j].z = 0.f; acc[i][j].w = 0.f; }

    for (int kc = 0; kc < C_; kc += 32) {
        __syncthreads();
#pragma unroll
        for (int it = 0; it < 4; ++it) {
            int flat = it * 256 + tid;
            int row = flat >> 3, ch = flat & 7;
            v4f wv4 = *reinterpret_cast<const v4f*>(w + (size_t)(o0 + row) * C_ + kc + ch * 4);
            uint2 pk;
            pk.x = f2bf(wv4.x * qscale) | ((unsigned)f2bf(wv4.y * qscale) << 16);
            pk.y = f2bf(wv4.z * qscale) | ((unsigned)f2bf(wv4.w * qscale) << 16);
            *reinterpret_cast<uint2*>(&w_lds[row * 40 + ch * 4]) = pk;
        }
#pragma unroll
        for (int it = 0; it < 4; ++it) {
            int flat = it * 256 + tid;
            int p = flat & 127;
            int cq = flat >> 7;
            const float* src = xb + (size_t)(kc + cq * 4) * P_ + p0 + p;
            float a0 = src[0], a1 = src[P_], a2 = src[2 * P_], a3 = src[3 * P_];
            uint2 pk;
            pk.x = f2bf(a0) | ((unsigned)f2bf(a1) << 16);
            pk.y = f2bf(a2) | ((unsigned)f2bf(a3) << 16);
            *reinterpret_cast<uint2*>(&x_lds[p * 40 + cq * 4]) = pk;
        }
        __syncthreads();
        v8s a[4];
#pragma unroll
        for (int mf = 0; mf < 4; ++mf)
            a[mf] = *reinterpret_cast<const v8s*>(&w_lds[(wo + mf * 16 + (l & 15)) * 40 + (l >> 4) * 8]);
#pragma unroll
        for (int nf = 0; nf < 4; ++nf) {
            v8s bf = *reinterpret_cast<const v8s*>(&x_lds[(wp + nf * 16 + (l & 15)) * 40 + (l >> 4) * 8]);
#pragma unroll
            for (int mf = 0; mf < 4; ++mf)
                acc[mf][nf] = __builtin_amdgcn_mfma_f32_16x16x32_bf16(a[mf], bf, acc[mf][nf], 0, 0, 0);
        }
    }
#pragma unroll
    for (int mf = 0; mf < 4; ++mf) {
        int ob = o0 + wo + mf * 16 + (l >> 4) * 4;
        v4f bi = *reinterpret_cast<const v4f*>(bias + ob);
#pragma unroll
        for (int nf = 0; nf < 4; ++nf) {
            int p = p0 + wp + nf * 16 + (l & 15);
            v4f v = acc[mf][nf];
            uint2 pk;
            pk.x = f2bf(v.x + bi.x * qscale) | ((unsigned)f2bf(v.y + bi.y * qscale) << 16);
            pk.y = f2bf(v.z + bi.z * qscale) | ((unsigned)f2bf(v.w + bi.w * qscale) << 16);
            *reinterpret_cast<uint2*>(&out[((size_t)b * P_ + p) * IC_ + ob]) = pk;
        }
    }
}

// ---------------- f = Q K^T passes, 3-buffer pipelined, counted vmcnt. ----------------
// grid 512 = (4 jchunks x 16 rowblocks x 8 b); 4 waves x 64 rows; 32 tiles of 32 j-cols.
template <int PASS>
__global__ __launch_bounds__(256, 2) void k_f(const u16* __restrict__ Q, const u16* __restrict__ K,
                                              float* __restrict__ srow, float* __restrict__ colsum) {
    __shared__ __align__(16) unsigned char smem[49152 + 4096 + 1024];
    float* colacc = (float*)(smem + 49152);      // [1024] per-block colsum accum
    float* cp = (float*)(smem + 49152 + 4096);   // [2 parity][4 wv][32]
    const int tid = threadIdx.x;
    const int l = tid & 63;
    const int wv = tid >> 6;
    // bijective XCD swizzle: all 64 blocks of one batch on one XCD
    int lin = blockIdx.x + blockIdx.y * 4 + blockIdx.z * 64;
    int nlin = (lin & 7) * 64 + (lin >> 3);
    const int jchunk = nlin & 3;
    const int yb = (nlin >> 2) & 15;
    const int b = nlin >> 6;
    const int i0 = yb * 256 + wv * 64;
    const int jbase = jchunk * 1024;
    const u16* Kb = K + (size_t)b * P_ * IC_;

    // A fragments: 64 rows x 256 ic in registers
    v8s a[4][8];
#pragma unroll
    for (int mf = 0; mf < 4; ++mf) {
        const u16* qrow = Q + ((size_t)b * P_ + i0 + mf * 16 + (l & 15)) * IC_ + (l >> 4) * 8;
#pragma unroll
        for (int s = 0; s < 8; ++s)
            a[mf][s] = *reinterpret_cast<const v8s*>(qrow + s * 32);
    }
    float racc[4][4];
    if (PASS == 1) {
#pragma unroll
        for (int mf = 0; mf < 4; ++mf)
#pragma unroll
            for (int r = 0; r < 4; ++r) racc[mf][r] = 0.f;
    } else {
#pragma unroll
        for (int mf = 0; mf < 4; ++mf) {
            v4f sr = *reinterpret_cast<const v4f*>(&srow[(size_t)b * P_ + i0 + mf * 16 + (l >> 4) * 4]);
            racc[mf][0] = 1.0f / sr.x;
            racc[mf][1] = 1.0f / sr.y;
            racc[mf][2] = 1.0f / sr.z;
            racc[mf][3] = 1.0f / sr.w;
        }
    }

    // stage tile t (32 cols x 256 ic = 16KB): linear LDS dest, inverse-swizzled global source
    auto stage = [&](int t, int buf) {
        int j0 = jbase + t * 32;
#pragma unroll
        for (int it = 0; it < 4; ++it) {
            int slot = wv * 4096 + it * 1024 + (l << 4);
            int row = slot >> 9;
            int brg = (slot & 511) ^ ((row & 7) << 4);
            gload_lds16((const unsigned char*)(Kb + (size_t)(j0 + row) * IC_) + brg,
                        smem + buf * 16384 + wv * 4096 + it * 1024);
        }
    };

    if (PASS == 2)
        for (int i = tid; i < 1024; i += 256) colacc[i] = 0.f;
    stage(0, 0);
    stage(1, 1);
    asm volatile("s_waitcnt vmcnt(4)" ::: "memory");  // tile 0 landed
    __builtin_amdgcn_sched_barrier(0);
    __builtin_amdgcn_s_barrier();
    __builtin_amdgcn_sched_barrier(0);

    int cur = 0;
    for (int t = 0; t < 32; ++t) {
        int nxt = cur + 2;
        if (nxt >= 3) nxt -= 3;
        if (t < 30) stage(t + 2, nxt);  // buffer of tile t-1, consumption certified by prev barrier
        if (PASS == 2 && t > 0 && tid < 32) {
            float* cpp = cp + ((t - 1) & 1) * 128;
            colacc[(t - 1) * 32 + tid] += cpp[tid] + cpp[32 + tid] + cpp[64 + tid] + cpp[96 + tid];
        }
        v4f acc[4][2];
#pragma unroll
        for (int mf = 0; mf < 4; ++mf)
#pragma unroll
            for (int nf = 0; nf < 2; ++nf) { acc[mf][nf].x = 0.f; acc[mf][nf].y = 0.f; acc[mf][nf].z = 0.f; acc[mf][nf].w = 0.f; }
        __builtin_amdgcn_s_setprio(1);
#pragma unroll
        for (int s = 0; s < 8; ++s) {
#pragma unroll
            for (int nf = 0; nf < 2; ++nf) {
                int row = nf * 16 + (l & 15);
                int byte_ = cur * 16384 + row * 512 + ((s * 64 + (l >> 4) * 16) ^ ((row & 7) << 4));
                v8s bf = *reinterpret_cast<const v8s*>(smem + byte_);
#pragma unroll
                for (int mf = 0; mf < 4; ++mf)
                    acc[mf][nf] = __builtin_amdgcn_mfma_f32_16x16x32_bf16(a[mf][s], bf, acc[mf][nf], 0, 0, 0);
            }
        }
        __builtin_amdgcn_s_setprio(0);
        if (PASS == 1) {
#pragma unroll
            for (int mf = 0; mf < 4; ++mf) {
#pragma unroll
                for (int nf = 0; nf < 2; ++nf) {
                    racc[mf][0] += exp2f(acc[mf][nf].x - MSHIFT2);
                    racc[mf][1] += exp2f(acc[mf][nf].y - MSHIFT2);
                    racc[mf][2] += exp2f(acc[mf][nf].z - MSHIFT2);
                    racc[mf][3] += exp2f(acc[mf][nf].w - MSHIFT2);
                }
            }
        } else {
            float c4[2];
#pragma unroll
            for (int nf = 0; nf < 2; ++nf) {
                float s_ = 0.f;
#pragma unroll
                for (int mf = 0; mf < 4; ++mf) {
                    s_ += exp2f(acc[mf][nf].x - MSHIFT2) * racc[mf][0];
                    s_ += exp2f(acc[mf][nf].y - MSHIFT2) * racc[mf][1];
                    s_ += exp2f(acc[mf][nf].z - MSHIFT2) * racc[mf][2];
                    s_ += exp2f(acc[mf][nf].w - MSHIFT2) * racc[mf][3];
                }
                s_ += __shfl_xor(s_, 16, 64);
                s_ += __shfl_xor(s_, 32, 64);
                c4[nf] = s_;
            }
            if (l < 32) cp[(t & 1) * 128 + wv * 32 + l] = (l >> 4) ? c4[1] : c4[0];
        }
        if (t < 30) {
            asm volatile("s_waitcnt vmcnt(4)" ::: "memory");  // tile t+1 landed; t+2 still in flight
        } else if (t == 30) {
            asm volatile("s_waitcnt vmcnt(0)" ::: "memory");  // last tile landed
        }
        __builtin_amdgcn_sched_barrier(0);
        __builtin_amdgcn_s_barrier();
        __builtin_amdgcn_sched_barrier(0);
        cur = (cur + 1 == 3) ? 0 : cur + 1;
    }

    if (PASS == 2) {
        if (tid < 32) {
            float* cpp = cp + (31 & 1) * 128;
            colacc[31 * 32 + tid] += cpp[tid] + cpp[32 + tid] + cpp[64 + tid] + cpp[96 + tid];
        }
        __syncthreads();
        for (int i = tid; i < 1024; i += 256)
            atomicAdd(&colsum[(size_t)b * P_ + jbase + i], colacc[i]);
    }
    if (PASS == 1) {
#pragma unroll
        for (int mf = 0; mf < 4; ++mf)
#pragma unroll
            for (int r = 0; r < 4; ++r) {
                float v = racc[mf][r];
                v += __shfl_xor(v, 1, 64);
                v += __shfl_xor(v, 2, 64);
                v += __shfl_xor(v, 4, 64);
                v += __shfl_xor(v, 8, 64);
                if ((l & 15) == 0)
                    atomicAdd(&srow[(size_t)b * P_ + i0 + mf * 16 + (l >> 4) * 4 + r], v);
            }
    }
}

// ---------------- vsum[b][o] = sum_c w_g[o][c]*Xsum[(b-1)%8][c] + P*b_g[o] ----------------
__global__ __launch_bounds__(256) void k_vsum(const float* __restrict__ w_g, const float* __restrict__ b_g,
                                              const float* __restrict__ Xsum, float* __restrict__ vsum) {
    __shared__ float xs[C_];
    int b = blockIdx.x;
    int bp = (b + B_ - 1) & 7;
    for (int i = threadIdx.x; i < C_; i += 256) xs[i] = Xsum[bp * C_ + i];
    __syncthreads();
    int o = threadIdx.x;
    const float* wr = w_g + (size_t)o * C_;
    float acc = 0.f;
    for (int c = 0; c < C_; c += 4) {
        v4f wv = *reinterpret_cast<const v4f*>(wr + c);
        acc += wv.x * xs[c] + wv.y * xs[c + 1] + wv.z * xs[c + 2] + wv.w * xs[c + 3];
    }
    vsum[b * IC_ + o] = acc + (float)P_ * b_g[o];
}

__global__ __launch_bounds__(512) void k_kd(const float* __restrict__ w_W, const float* __restrict__ b_W,
                                            const float* __restrict__ vsum, float* __restrict__ Kv, float* __restrict__ Dv) {
    __shared__ float vs[IC_];
    int b = blockIdx.x;
    for (int i = threadIdx.x; i < IC_; i += 512) vs[i] = vsum[b * IC_ + i];
    __syncthreads();
    int o = threadIdx.x;
    const float* wr = w_W + (size_t)o * (2 * IC_);
    float a = 0.f, bv = 0.f;
    for (int ic = 0; ic < IC_; ic += 4) {
        v4f w1 = *reinterpret_cast<const v4f*>(wr + ic);
        v4f w2 = *reinterpret_cast<const v4f*>(wr + IC_ + ic);
        a += w1.x * vs[ic] + w1.y * vs[ic + 1] + w1.z * vs[ic + 2] + w1.w * vs[ic + 3];
        bv += w2.x * vs[ic] + w2.y * vs[ic + 1] + w2.z * vs[ic + 2] + w2.w * vs[ic + 3];
    }
    Kv[b * C_ + o] = bv + b_W[o];
    Dv[b * C_ + o] = a - bv;
}

__global__ __launch_bounds__(256) void k_s12(const float* __restrict__ colsum, float* __restrict__ s12) {
    int b = blockIdx.x;
    const float invP = 1.0f / P_;
    float s1 = 0.f, s2 = 0.f;
    for (int k = threadIdx.x * 4; k < P_; k += 1024) {
        v4f v = *reinterpret_cast<const v4f*>(colsum + (size_t)b * P_ + k);
        float m0 = v.x * invP, m1 = v.y * invP, m2 = v.z * invP, m3 = v.w * invP;
        s1 += m0 + m1 + m2 + m3;
        s2 += m0 * m0 + m1 * m1 + m2 * m2 + m3 * m3;
    }
    for (int off = 1; off < 64; off <<= 1) {
        s1 += __shfl_xor(s1, off, 64);
        s2 += __shfl_xor(s2, off, 64);
    }
    __shared__ float p1[4], p2[4];
    if ((threadIdx.x & 63) == 0) { p1[threadIdx.x >> 6] = s1; p2[threadIdx.x >> 6] = s2; }
    __syncthreads();
    if (threadIdx.x == 0) {
        s12[b * 2] = p1[0] + p1[1] + p1[2] + p1[3];
        s12[b * 2 + 1] = p2[0] + p2[1] + p2[2] + p2[3];
    }
}

__global__ __launch_bounds__(512) void k_bn(const float* __restrict__ Kv, const float* __restrict__ Dv,
                                            const float* __restrict__ s12, const float* __restrict__ gamma,
                                            const float* __restrict__ beta, float* __restrict__ alpha, float* __restrict__ ofs) {
    int o = threadIdx.x;
    const float invP = 1.0f / P_;
    float mu = 0.f, e2 = 0.f;
#pragma unroll
    for (int b = 0; b < B_; ++b) {
        float Kx = Kv[b * C_ + o], Dx = Dv[b * C_ + o];
        float m1 = s12[b * 2] * invP;
        float m2 = s12[b * 2 + 1] * invP;
        mu += Kx + Dx * m1;
        e2 += Kx * Kx + 2.f * Kx * Dx * m1 + Dx * Dx * m2;
    }
    mu *= 0.125f;
    e2 *= 0.125f;
    float var = e2 - mu * mu;
    float gi = gamma[o] * rsqrtf(var + 1e-5f);
    float bo = beta[o];
#pragma unroll
    for (int b = 0; b < B_; ++b) {
        alpha[b * C_ + o] = gi * Dv[b * C_ + o] * invP;
        ofs[b * C_ + o] = gi * (Kv[b * C_ + o] - mu) + bo;
    }
}

__global__ __launch_bounds__(256) void k_out(const float* __restrict__ x, const float* __restrict__ colsum,
                                             const float* __restrict__ alpha, const float* __restrict__ ofs,
                                             float* __restrict__ out) {
    int bo = blockIdx.x;
    int b = bo >> 9;
    float al = alpha[bo], of = ofs[bo];
    size_t base = (size_t)bo * P_;
    const float* cb = colsum + (size_t)b * P_;
#pragma unroll
    for (int q = 0; q < 4; ++q) {
        int p = q * 1024 + threadIdx.x * 4;
        v4f xv = *reinterpret_cast<const v4f*>(x + base + p);
        v4f cs = *reinterpret_cast<const v4f*>(cb + p);
        v4f r;
        r.x = of + al * cs.x + xv.x;
        r.y = of + al * cs.y + xv.y;
        r.z = of + al * cs.z + xv.z;
        r.w = of + al * cs.w + xv.w;
        *reinterpret_cast<v4f*>(out + base + p) = r;
    }
}

extern "C" void kernel_launch(void* const* d_in, const int* in_sizes, int n_in,
                              void* d_out, int out_size, void* d_ws, size_t ws_size,
                              hipStream_t stream) {
    const float* x = (const float*)d_in[0];
    const float* w_theta = (const float*)d_in[1];
    const float* b_theta = (const float*)d_in[2];
    const float* w_phi = (const float*)d_in[3];
    const float* b_phi = (const float*)d_in[4];
    const float* w_g = (const float*)d_in[5];
    const float* b_g = (const float*)d_in[6];
    const float* w_W = (const float*)d_in[7];
    const float* b_W = (const float*)d_in[8];
    const float* gamma = (const float*)d_in[9];
    const float* beta = (const float*)d_in[10];
    float* out = (float*)d_out;

    u16* Q = (u16*)d_ws;
    u16* K = Q + (size_t)B_ * P_ * IC_;
    float* fb = (float*)((char*)d_ws + (size_t)2 * B_ * P_ * IC_ * 2);
    float* srow = fb;
    float* colsum = srow + B_ * P_;
    float* Xsum = colsum + B_ * P_;
    float* vsum = Xsum + B_ * C_;
    float* Kv = vsum + B_ * IC_;
    float* Dv = Kv + B_ * C_;
    float* s12 = Dv + B_ * C_;
    float* alpha = s12 + 16;
    float* ofs = alpha + B_ * C_;

    hipMemsetAsync(srow, 0, sizeof(float) * 2 * B_ * P_, stream);
    k_xsum<<<B_ * C_, 256, 0, stream>>>(x, Xsum);
    k_qk<<<dim3(32, 2, 16), 256, 0, stream>>>(w_theta, b_theta, w_phi, b_phi, x, Q, K);
    k_vsum<<<B_, 256, 0, stream>>>(w_g, b_g, Xsum, vsum);
    k_kd<<<B_, 512, 0, stream>>>(w_W, b_W, vsum, Kv, Dv);
    k_f<1><<<dim3(4, 16, 8), 256, 0, stream>>>(Q, K, srow, colsum);
    k_f<2><<<dim3(4, 16, 8), 256, 0, stream>>>(Q, K, srow, colsum);
    k_s12<<<B_, 256, 0, stream>>>(colsum, s12);
    k_bn<<<1, 512, 0, stream>>>(Kv, Dv, s12, gamma, beta, alpha, ofs);
    k_out<<<B_ * C_, 256, 0, stream>>>(x, colsum, alpha, ofs, out);
}